// Round 5
// baseline (17033.911 us; speedup 1.0000x reference)
//
#include <hip/hip_runtime.h>

typedef __attribute__((ext_vector_type(8))) short short8;
typedef __attribute__((ext_vector_type(4))) float f32x4;
typedef unsigned long long u64;

#define T_STEPS 512
#define BATCH 64
#define HID 1024
#define NWG 64
#define WROW 1032  // padded LDS row stride in shorts: 2064 B, 16B-aligned

__device__ __forceinline__ unsigned short f2bf(float f) {
  union { float f; unsigned u; } v; v.f = f;
  return (unsigned short)((v.u + 0x7FFFu + ((v.u >> 16) & 1u)) >> 16);
}

__device__ __forceinline__ u64 pack4bf(float a, float b, float c, float d) {
  return (u64)f2bf(a) | ((u64)f2bf(b) << 16) | ((u64)f2bf(c) << 32) | ((u64)f2bf(d) << 48);
}

// ---- exchange load: sc0 (L1 bypass) + L2 CACHED. Freshness from the per-phase
// agent acquire-fence (buffer_inv) in gbar_wait; L2 caching restores 128B-line
// coalescing so the 8 WGs of an XCD share line fetches instead of issuing
// 8192x16B uncached granule requests per CU per phase.
#define LD16(dst, p, OFS)                                                 \
  asm volatile("global_load_dwordx4 %0, %1, off offset:" #OFS " sc0"      \
               : "=v"(dst) : "v"(p))

// issue 32 x 16B loads back-to-back, ALL in flight -> one round trip after VMWAIT0()
__device__ __forceinline__ void burst32(short8 hb[32], const unsigned short* p) {
  LD16(hb[0], p, 0);     LD16(hb[1], p, 64);    LD16(hb[2], p, 128);   LD16(hb[3], p, 192);
  LD16(hb[4], p, 256);   LD16(hb[5], p, 320);   LD16(hb[6], p, 384);   LD16(hb[7], p, 448);
  LD16(hb[8], p, 512);   LD16(hb[9], p, 576);   LD16(hb[10], p, 640);  LD16(hb[11], p, 704);
  LD16(hb[12], p, 768);  LD16(hb[13], p, 832);  LD16(hb[14], p, 896);  LD16(hb[15], p, 960);
  LD16(hb[16], p, 1024); LD16(hb[17], p, 1088); LD16(hb[18], p, 1152); LD16(hb[19], p, 1216);
  LD16(hb[20], p, 1280); LD16(hb[21], p, 1344); LD16(hb[22], p, 1408); LD16(hb[23], p, 1472);
  LD16(hb[24], p, 1536); LD16(hb[25], p, 1600); LD16(hb[26], p, 1664); LD16(hb[27], p, 1728);
  LD16(hb[28], p, 1792); LD16(hb[29], p, 1856); LD16(hb[30], p, 1920); LD16(hb[31], p, 1984);
}

// wait for all VMEM, and fence the scheduler so no consumer is hoisted above (rule #18)
#define VMWAIT0()                                          \
  do {                                                     \
    asm volatile("s_waitcnt vmcnt(0)" ::: "memory");       \
    __builtin_amdgcn_sched_barrier(0);                     \
  } while (0)

// write-through stores (no dirty L2 lines anywhere in this kernel -> the per-phase
// buffer_inv can never discard unwritten data)
__device__ __forceinline__ void st8_dev(unsigned short* p, u64 v) {
  asm volatile("global_store_dwordx2 %0, %1, off sc0 sc1" :: "v"(p), "v"(v) : "memory");
}
__device__ __forceinline__ void st16_dev(float* p, f32x4 v) {
  asm volatile("global_store_dwordx4 %0, %1, off sc0 sc1" :: "v"(p), "v"(v) : "memory");
}

// ---------------- conversion ----------------
__global__ void k_f32_to_bf16(const float* __restrict__ src,
                              unsigned short* __restrict__ dst, int n4) {
  int i = blockIdx.x * blockDim.x + threadIdx.x;
  if (i >= n4) return;
  float4 v = ((const float4*)src)[i];
  unsigned long long p = (unsigned long long)f2bf(v.x)
                       | ((unsigned long long)f2bf(v.y) << 16)
                       | ((unsigned long long)f2bf(v.z) << 32)
                       | ((unsigned long long)f2bf(v.w) << 48);
  ((unsigned long long*)dst)[i] = p;
}

__global__ void k_sentinel(float* out) { out[threadIdx.x] = 12345.0f; }

// ---------------- big GEMM: C(M,N) = A(M,K) * B(N,K)^T + bias(N) ----------------
__global__ __launch_bounds__(256) void k_gemm_bias(
    const unsigned short* __restrict__ A,
    const unsigned short* __restrict__ Bm,
    const float* __restrict__ bias,
    float* __restrict__ C) {
  constexpr int K = 1024, N = 3072;
  constexpr int LS = 40;
  __shared__ unsigned short As[128 * LS];
  __shared__ unsigned short Bs[128 * LS];
  const int tid = threadIdx.x;
  const int lane = tid & 63;
  const int w = tid >> 6;
  const int wm = (w >> 1) * 64, wn = (w & 1) * 64;
  const int m0 = blockIdx.y * 128, n0 = blockIdx.x * 128;
  const int q = lane >> 4, ln = lane & 15;
  const int r = tid >> 2;
  const int c8 = (tid & 3) * 8;

  f32x4 acc[4][4] = {};

  for (int k0 = 0; k0 < K; k0 += 32) {
#pragma unroll
    for (int p = 0; p < 2; ++p) {
      int row = r + p * 64;
      *(short8*)&As[row * LS + c8] = *(const short8*)&A[(long)(m0 + row) * K + k0 + c8];
      *(short8*)&Bs[row * LS + c8] = *(const short8*)&Bm[(long)(n0 + row) * K + k0 + c8];
    }
    __syncthreads();
    short8 af[4], bfr[4];
#pragma unroll
    for (int i = 0; i < 4; ++i) af[i] = *(short8*)&As[(wm + i * 16 + ln) * LS + q * 8];
#pragma unroll
    for (int i = 0; i < 4; ++i) bfr[i] = *(short8*)&Bs[(wn + i * 16 + ln) * LS + q * 8];
#pragma unroll
    for (int im = 0; im < 4; ++im)
#pragma unroll
      for (int in = 0; in < 4; ++in)
        acc[im][in] = __builtin_amdgcn_mfma_f32_16x16x32_bf16(af[im], bfr[in], acc[im][in], 0, 0, 0);
    __syncthreads();
  }
#pragma unroll
  for (int im = 0; im < 4; ++im) {
    int mrow = m0 + wm + im * 16 + q * 4;
#pragma unroll
    for (int in = 0; in < 4; ++in) {
      int ncol = n0 + wn + in * 16 + ln;
      float bv = bias[ncol];
#pragma unroll
      for (int j = 0; j < 4; ++j)
        C[(long)(mrow + j) * N + ncol] = acc[im][in][j] + bv;
    }
  }
}

// ---------------- flag-array grid barrier ----------------
__device__ __forceinline__ void gbar_arrive(unsigned* flags, unsigned gen, int wgid) {
  asm volatile("s_waitcnt vmcnt(0)" ::: "memory");
  __syncthreads();  // every wave drained its own vmcnt before the s_barrier
  if (threadIdx.x == 0)
    __hip_atomic_store(&flags[wgid], gen, __ATOMIC_RELAXED, __HIP_MEMORY_SCOPE_AGENT);
}
__device__ __forceinline__ void gbar_wait(unsigned* flags, unsigned gen) {
  if (threadIdx.x < NWG) {
    long spins = 0;
    while (__hip_atomic_load(&flags[threadIdx.x], __ATOMIC_RELAXED,
                             __HIP_MEMORY_SCOPE_AGENT) < gen) {
      if (++spins > (1L << 20)) {  // failsafe: wrong answer beats a hang
        __hip_atomic_store(&flags[threadIdx.x], 0xFFFFFFFFu, __ATOMIC_RELAXED,
                           __HIP_MEMORY_SCOPE_AGENT);
        break;
      }
    }
  }
  __syncthreads();
  // invalidate this XCD's (non-coherent) L1/L2 so the following cached burst
  // reads fresh IC data. All stores in this kernel are write-through, so the
  // inv can never discard unwritten data.
  __builtin_amdgcn_fence(__ATOMIC_ACQUIRE, "agent");
}

// ---------------- persistent GRU recurrence ----------------
// 64 WGs x 256 thr. WG owns 16 output features; weights LDS-resident.
// Operand-swapped MFMA: D = W * h^T; thread (q,ln) of wave wv owns
// batch row R = wv*16+ln, features F..F+3 (F = c0+q*4): state in registers.
// h/hr exchange: L2-cached sc0 bursts + per-phase acquire-fence; WT stores.
__global__ __launch_bounds__(256, 1) void k_gru_rec(
    const float* __restrict__ gx,           // (T,B,3,H) fp32
    const unsigned short* __restrict__ Wh,  // (3,H,H) bf16, this layer
    unsigned short* __restrict__ h16,       // (B,H) bf16 state (IC-coherent)
    unsigned short* __restrict__ hr16,      // (B,H) bf16 h*r   (IC-coherent)
    unsigned short* __restrict__ ys16,      // (T,B,H) bf16 (written when layer==0)
    float* __restrict__ outh,               // (T,B,H) fp32 (written when layer==1)
    float* __restrict__ outs,               // (B,H) fp32 state slice for this layer
    unsigned* __restrict__ bar, int layer) {
  __shared__ unsigned short Ws[3 * 16 * WROW];  // 99,072 B
  const int tid = threadIdx.x;
  const int lane = tid & 63;
  const int wv = tid >> 6;
  const int q = lane >> 4, ln = lane & 15;
  const int c0 = blockIdx.x * 16;
  const int wgid = blockIdx.x;

  // stage weight slices: 3 gates x 16 rows x 1024 k
  for (int i = tid; i < 3 * 16 * 128; i += 256) {
    int g = i >> 11;
    int rem = i & 2047;
    int row = rem >> 7;
    int k8 = (rem & 127) * 8;
    *(short8*)&Ws[g * (16 * WROW) + row * WROW + k8] =
        *(const short8*)&Wh[((long)g * HID + (c0 + row)) * HID + k8];
  }
  __syncthreads();

  const int R = wv * 16 + ln;  // owned batch row
  const int F = c0 + q * 4;    // owned feature base
  const unsigned short* wpr = &Ws[0 * (16 * WROW) + ln * WROW + q * 8];
  const unsigned short* wpz = &Ws[1 * (16 * WROW) + ln * WROW + q * 8];
  const unsigned short* wpc = &Ws[2 * (16 * WROW) + ln * WROW + q * 8];
  const unsigned short* hp1 = h16 + (long)R * HID + q * 8;   // burst base (h)
  const unsigned short* hp2 = hr16 + (long)R * HID + q * 8;  // burst base (h*r)

  f32x4 h_st = {0.f, 0.f, 0.f, 0.f};
  f32x4 pg_r, pg_z, pg_c;
  {  // prefetch gx for t=0
    const float* g0 = &gx[((long)R * 3) * HID + F];
    pg_r = *(const f32x4*)(g0);
    pg_z = *(const f32x4*)(g0 + HID);
    pg_c = *(const f32x4*)(g0 + 2 * HID);
  }

  unsigned gen = 0;
  short8 hb[32];

  for (int t = 0; t < T_STEPS; ++t) {
    // ---- phase 1: r (critical), z (overlapped with barrier wait) ----
    burst32(hb, hp1);
    VMWAIT0();
    f32x4 ar0 = {0.f, 0.f, 0.f, 0.f}, ar1 = {0.f, 0.f, 0.f, 0.f};
#pragma unroll
    for (int kk = 0; kk < 32; ++kk) {
      short8 w = *(const short8*)(wpr + kk * 32);
      if (kk & 1) ar1 = __builtin_amdgcn_mfma_f32_16x16x32_bf16(w, hb[kk], ar1, 0, 0, 0);
      else        ar0 = __builtin_amdgcn_mfma_f32_16x16x32_bf16(w, hb[kk], ar0, 0, 0, 0);
    }
    {
      f32x4 accr = ar0 + ar1;
      float v0 = h_st[0] * (1.0f / (1.0f + __expf(-(pg_r[0] + accr[0]))));
      float v1 = h_st[1] * (1.0f / (1.0f + __expf(-(pg_r[1] + accr[1]))));
      float v2 = h_st[2] * (1.0f / (1.0f + __expf(-(pg_r[2] + accr[2]))));
      float v3 = h_st[3] * (1.0f / (1.0f + __expf(-(pg_r[3] + accr[3]))));
      st8_dev(hr16 + (long)R * HID + F, pack4bf(v0, v1, v2, v3));
    }
    ++gen;
    gbar_arrive(bar, gen, wgid);
    // z-chain overlapped with flag-visibility + poll (off critical path)
    f32x4 az = {0.f, 0.f, 0.f, 0.f};
#pragma unroll
    for (int kk = 0; kk < 32; ++kk) {
      short8 w = *(const short8*)(wpz + kk * 32);
      az = __builtin_amdgcn_mfma_f32_16x16x32_bf16(w, hb[kk], az, 0, 0, 0);
    }
    gbar_wait(bar, gen);

    // ---- phase 2: c + state update ----
    burst32(hb, hp2);
    VMWAIT0();
    f32x4 ac0 = {0.f, 0.f, 0.f, 0.f}, ac1 = {0.f, 0.f, 0.f, 0.f};
#pragma unroll
    for (int kk = 0; kk < 32; ++kk) {
      short8 w = *(const short8*)(wpc + kk * 32);
      if (kk & 1) ac1 = __builtin_amdgcn_mfma_f32_16x16x32_bf16(w, hb[kk], ac1, 0, 0, 0);
      else        ac0 = __builtin_amdgcn_mfma_f32_16x16x32_bf16(w, hb[kk], ac0, 0, 0, 0);
    }
    long pos = (long)R * HID + F;
    long opos = ((long)t * BATCH + R) * HID + F;
    f32x4 hnv;
    u64 pk;
    {
      f32x4 accc = ac0 + ac1;
      unsigned short hq[4];
#pragma unroll
      for (int j = 0; j < 4; ++j) {
        float zz = 1.0f / (1.0f + __expf(-(pg_z[j] + az[j])));
        float cc = tanhf(pg_c[j] + accc[j]);
        float hn = zz * h_st[j] + (1.0f - zz) * cc;
        h_st[j] = hn; hnv[j] = hn; hq[j] = f2bf(hn);
      }
      pk = (u64)hq[0] | ((u64)hq[1] << 16) | ((u64)hq[2] << 32) | ((u64)hq[3] << 48);
      st8_dev(h16 + pos, pk);
    }
    ++gen;
    gbar_arrive(bar, gen, wgid);
    // off-critical-path work hidden under flag-visibility + poll:
    if (layer == 0) st8_dev(&ys16[opos], pk);       // write-through (no dirty L2)
    else            st16_dev(&outh[opos], hnv);     // write-through
    if (t == T_STEPS - 1) st16_dev(&outs[pos], hnv);
    if (t + 1 < T_STEPS) {  // gx prefetch for t+1 (register prefetch, fence-immune)
      const float* g1 = &gx[(((long)(t + 1) * BATCH + R) * 3) * HID + F];
      pg_r = *(const f32x4*)(g1);
      pg_z = *(const f32x4*)(g1 + HID);
      pg_c = *(const f32x4*)(g1 + 2 * HID);
    }
    gbar_wait(bar, gen);
  }
}

// ---------------- launch ----------------
extern "C" void kernel_launch(void* const* d_in, const int* in_sizes, int n_in,
                              void* d_out, int out_size, void* d_ws, size_t ws_size,
                              hipStream_t stream) {
  const float* x = (const float*)d_in[0];
  const float* Wx = (const float*)d_in[1];
  const float* bx = (const float*)d_in[2];
  const float* Wh = (const float*)d_in[3];
  float* out = (float*)d_out;

  const size_t SZ_GX = (size_t)T_STEPS * BATCH * 3 * HID * 4;   // 402,653,184
  const size_t SZ_HID = (size_t)T_STEPS * BATCH * HID * 2;      // 67,108,864
  const size_t SZ_W16 = (size_t)2 * 3 * HID * HID * 2;          // 12,582,912
  const size_t NEEDED = SZ_GX + SZ_HID + 2 * SZ_W16 +
                        2 * (size_t)BATCH * HID * 2 + 256;
  if (ws_size < NEEDED) {
    k_sentinel<<<1, 64, 0, stream>>>(out);
    return;
  }

  char* ws = (char*)d_ws;
  size_t off = 0;
  float* gx32 = (float*)(ws + off); off += SZ_GX;
  unsigned short* hid16 = (unsigned short*)(ws + off); off += SZ_HID;
  unsigned short* Wx16 = (unsigned short*)(ws + off); off += SZ_W16;
  unsigned short* Wh16 = (unsigned short*)(ws + off); off += SZ_W16;
  unsigned short* h16 = (unsigned short*)(ws + off); off += (size_t)BATCH * HID * 2;
  unsigned short* hr16 = (unsigned short*)(ws + off); off += (size_t)BATCH * HID * 2;
  unsigned* bar = (unsigned*)(ws + off); off += 256;

  {
    int n4 = T_STEPS * BATCH * HID / 4;
    k_f32_to_bf16<<<(n4 + 255) / 256, 256, 0, stream>>>(x, hid16, n4);
  }
  {
    int n4 = 2 * 3 * HID * HID / 4;
    k_f32_to_bf16<<<(n4 + 255) / 256, 256, 0, stream>>>(Wx, Wx16, n4);
    k_f32_to_bf16<<<(n4 + 255) / 256, 256, 0, stream>>>(Wh, Wh16, n4);
  }

  float* outh = out;
  float* outs = out + (size_t)T_STEPS * BATCH * HID;

  for (int l = 0; l < 2; ++l) {
    k_gemm_bias<<<dim3(3072 / 128, 32768 / 128), 256, 0, stream>>>(
        hid16, Wx16 + (size_t)l * 3 * HID * HID, bx + (size_t)l * 3 * HID, gx32);
    hipMemsetAsync(h16, 0, (size_t)BATCH * HID * 2, stream);
    hipMemsetAsync(bar, 0, 256, stream);
    k_gru_rec<<<NWG, 256, 0, stream>>>(
        gx32, Wh16 + (size_t)l * 3 * HID * HID, h16, hr16,
        hid16, outh, outs + (size_t)l * BATCH * HID, bar, l);
  }
}

// Round 6
// 13148.250 us; speedup vs baseline: 1.2955x; 1.2955x over previous
//
#include <hip/hip_runtime.h>

typedef __attribute__((ext_vector_type(8))) short short8;
typedef __attribute__((ext_vector_type(4))) float f32x4;
typedef unsigned long long u64;

#define T_STEPS 512
#define BATCH 64
#define HID 1024
#define NWG 64
#define WROW 1032  // padded LDS row stride in shorts: 2064 B, 16B-aligned
#define HROW 136   // staged h-tile row stride in shorts (128 + 8 pad)
#define KC 128     // k-columns per staged chunk

__device__ __forceinline__ unsigned short f2bf(float f) {
  union { float f; unsigned u; } v; v.f = f;
  return (unsigned short)((v.u + 0x7FFFu + ((v.u >> 16) & 1u)) >> 16);
}

__device__ __forceinline__ u64 pack4bf(float a, float b, float c, float d) {
  return (u64)f2bf(a) | ((u64)f2bf(b) << 16) | ((u64)f2bf(c) << 32) | ((u64)f2bf(d) << 48);
}

// ---- device-coherent 16B load: sc0 (L1 bypass) + sc1 (L2 bypass) -> reads IC ----
// (round-4 proven protocol; freshness requires BOTH bits)
#define LD16(dst, p, OFS)                                                     \
  asm volatile("global_load_dwordx4 %0, %1, off offset:" #OFS " sc0 sc1"      \
               : "=v"(dst) : "v"(p))

// wait for all VMEM, and fence the scheduler so no consumer is hoisted above (rule #18)
#define VMWAIT0()                                          \
  do {                                                     \
    asm volatile("s_waitcnt vmcnt(0)" ::: "memory");       \
    __builtin_amdgcn_sched_barrier(0);                     \
  } while (0)

__device__ __forceinline__ void st8_dev(unsigned short* p, u64 v) {
  asm volatile("global_store_dwordx2 %0, %1, off sc0 sc1" :: "v"(p), "v"(v) : "memory");
}
__device__ __forceinline__ void st16_dev(float* p, f32x4 v) {
  asm volatile("global_store_dwordx4 %0, %1, off sc0 sc1" :: "v"(p), "v"(v) : "memory");
}

// ---------------- conversion ----------------
__global__ void k_f32_to_bf16(const float* __restrict__ src,
                              unsigned short* __restrict__ dst, int n4) {
  int i = blockIdx.x * blockDim.x + threadIdx.x;
  if (i >= n4) return;
  float4 v = ((const float4*)src)[i];
  unsigned long long p = (unsigned long long)f2bf(v.x)
                       | ((unsigned long long)f2bf(v.y) << 16)
                       | ((unsigned long long)f2bf(v.z) << 32)
                       | ((unsigned long long)f2bf(v.w) << 48);
  ((unsigned long long*)dst)[i] = p;
}

__global__ void k_sentinel(float* out) { out[threadIdx.x] = 12345.0f; }

// ---------------- big GEMM: C(M,N) = A(M,K) * B(N,K)^T + bias(N) ----------------
__global__ __launch_bounds__(256) void k_gemm_bias(
    const unsigned short* __restrict__ A,
    const unsigned short* __restrict__ Bm,
    const float* __restrict__ bias,
    float* __restrict__ C) {
  constexpr int K = 1024, N = 3072;
  constexpr int LS = 40;
  __shared__ unsigned short As[128 * LS];
  __shared__ unsigned short Bs[128 * LS];
  const int tid = threadIdx.x;
  const int lane = tid & 63;
  const int w = tid >> 6;
  const int wm = (w >> 1) * 64, wn = (w & 1) * 64;
  const int m0 = blockIdx.y * 128, n0 = blockIdx.x * 128;
  const int q = lane >> 4, ln = lane & 15;
  const int r = tid >> 2;
  const int c8 = (tid & 3) * 8;

  f32x4 acc[4][4] = {};

  for (int k0 = 0; k0 < K; k0 += 32) {
#pragma unroll
    for (int p = 0; p < 2; ++p) {
      int row = r + p * 64;
      *(short8*)&As[row * LS + c8] = *(const short8*)&A[(long)(m0 + row) * K + k0 + c8];
      *(short8*)&Bs[row * LS + c8] = *(const short8*)&Bm[(long)(n0 + row) * K + k0 + c8];
    }
    __syncthreads();
    short8 af[4], bfr[4];
#pragma unroll
    for (int i = 0; i < 4; ++i) af[i] = *(short8*)&As[(wm + i * 16 + ln) * LS + q * 8];
#pragma unroll
    for (int i = 0; i < 4; ++i) bfr[i] = *(short8*)&Bs[(wn + i * 16 + ln) * LS + q * 8];
#pragma unroll
    for (int im = 0; im < 4; ++im)
#pragma unroll
      for (int in = 0; in < 4; ++in)
        acc[im][in] = __builtin_amdgcn_mfma_f32_16x16x32_bf16(af[im], bfr[in], acc[im][in], 0, 0, 0);
    __syncthreads();
  }
#pragma unroll
  for (int im = 0; im < 4; ++im) {
    int mrow = m0 + wm + im * 16 + q * 4;
#pragma unroll
    for (int in = 0; in < 4; ++in) {
      int ncol = n0 + wn + in * 16 + ln;
      float bv = bias[ncol];
#pragma unroll
      for (int j = 0; j < 4; ++j)
        C[(long)(mrow + j) * N + ncol] = acc[im][in][j] + bv;
    }
  }
}

// ---------------- flag-array grid barrier (round-4 proven) ----------------
__device__ __forceinline__ void gbar_arrive(unsigned* flags, unsigned gen, int wgid) {
  asm volatile("s_waitcnt vmcnt(0)" ::: "memory");
  __syncthreads();  // every wave drained its own vmcnt before the s_barrier
  if (threadIdx.x == 0)
    __hip_atomic_store(&flags[wgid], gen, __ATOMIC_RELAXED, __HIP_MEMORY_SCOPE_AGENT);
}
__device__ __forceinline__ void gbar_wait(unsigned* flags, unsigned gen) {
  if (threadIdx.x < NWG) {
    long spins = 0;
    while (__hip_atomic_load(&flags[threadIdx.x], __ATOMIC_RELAXED,
                             __HIP_MEMORY_SCOPE_AGENT) < gen) {
      if (++spins > (1L << 20)) {  // failsafe: wrong answer beats a hang
        __hip_atomic_store(&flags[threadIdx.x], 0xFFFFFFFFu, __ATOMIC_RELAXED,
                           __HIP_MEMORY_SCOPE_AGENT);
        break;
      }
    }
  }
  __syncthreads();
}

// ---------------- staged gate chain ----------------
// Coalesced cooperative load of src (B x HID bf16) in 8 k-chunks of [64][KC]
// into double-buffered padded LDS tiles, then fragment ds_reads + MFMA.
// Wave-instruction of the staging load covers 4 rows x 256 B contiguous
// -> 8 cache-line requests (vs 64 granule requests for the direct fragment load).
__device__ __forceinline__ void staged_chain(
    const unsigned short* __restrict__ src,  // h16 or hr16
    const unsigned short* __restrict__ wp,   // per-lane weight base (LDS)
    unsigned short* __restrict__ HsA, unsigned short* __restrict__ HsB,
    int tid, int frow, int lofs, short8 hb[32], f32x4& a0, f32x4& a1) {
  const unsigned short* gb = src + (tid >> 4) * HID + (tid & 15) * 8;
  short8 sg0, sg1, sg2, sg3;
  // prologue: chunk 0
  LD16(sg0, gb, 0);
  LD16(sg1, gb + 16 * HID, 0);
  LD16(sg2, gb + 32 * HID, 0);
  LD16(sg3, gb + 48 * HID, 0);
  VMWAIT0();
  *(short8*)&HsA[lofs] = sg0;
  *(short8*)&HsA[lofs + 16 * HROW] = sg1;
  *(short8*)&HsA[lofs + 32 * HROW] = sg2;
  *(short8*)&HsA[lofs + 48 * HROW] = sg3;
  __syncthreads();
#pragma unroll
  for (int j = 0; j < 8; ++j) {
    unsigned short* cur = (j & 1) ? HsB : HsA;
    unsigned short* nxt = (j & 1) ? HsA : HsB;
    if (j < 7) {  // issue next chunk's global loads; RT hides under this chunk's work
      const unsigned short* gk = gb + (j + 1) * KC;
      LD16(sg0, gk, 0);
      LD16(sg1, gk + 16 * HID, 0);
      LD16(sg2, gk + 32 * HID, 0);
      LD16(sg3, gk + 48 * HID, 0);
    }
#pragma unroll
    for (int u = 0; u < 4; ++u) hb[j * 4 + u] = *(const short8*)&cur[frow + u * 32];
#pragma unroll
    for (int u = 0; u < 4; ++u) {
      short8 w = *(const short8*)(wp + (j * 4 + u) * 32);
      if (u & 1) a1 = __builtin_amdgcn_mfma_f32_16x16x32_bf16(w, hb[j * 4 + u], a1, 0, 0, 0);
      else       a0 = __builtin_amdgcn_mfma_f32_16x16x32_bf16(w, hb[j * 4 + u], a0, 0, 0, 0);
    }
    if (j < 7) {
      VMWAIT0();
      *(short8*)&nxt[lofs] = sg0;
      *(short8*)&nxt[lofs + 16 * HROW] = sg1;
      *(short8*)&nxt[lofs + 32 * HROW] = sg2;
      *(short8*)&nxt[lofs + 48 * HROW] = sg3;
      __syncthreads();  // one barrier per chunk: write(nxt) -> read(nxt) next iter
    }
  }
}

// ---------------- persistent GRU recurrence ----------------
// 64 WGs x 256 thr. WG owns 16 output features; weights LDS-resident.
// Operand-swapped MFMA: D = W * h^T; thread (q,ln) of wave wv owns
// batch row R = wv*16+ln, features F..F+3 (F = c0+q*4): state in registers.
// Exchange: coalesced LDS-staged uncached loads + sc0+sc1 WT stores (round-4 protocol).
__global__ __launch_bounds__(256, 1) void k_gru_rec(
    const float* __restrict__ gx,           // (T,B,3,H) fp32
    const unsigned short* __restrict__ Wh,  // (3,H,H) bf16, this layer
    unsigned short* __restrict__ h16,       // (B,H) bf16 state (IC-coherent)
    unsigned short* __restrict__ hr16,      // (B,H) bf16 h*r   (IC-coherent)
    unsigned short* __restrict__ ys16,      // (T,B,H) bf16 (written when layer==0)
    float* __restrict__ outh,               // (T,B,H) fp32 (written when layer==1)
    float* __restrict__ outs,               // (B,H) fp32 state slice for this layer
    unsigned* __restrict__ bar, int layer) {
  __shared__ unsigned short Ws[3 * 16 * WROW];  // 99,072 B
  __shared__ unsigned short Hs[2][64 * HROW];   // 34,816 B staged h tiles
  const int tid = threadIdx.x;
  const int lane = tid & 63;
  const int wv = tid >> 6;
  const int q = lane >> 4, ln = lane & 15;
  const int c0 = blockIdx.x * 16;
  const int wgid = blockIdx.x;

  // stage weight slices: 3 gates x 16 rows x 1024 k
  for (int i = tid; i < 3 * 16 * 128; i += 256) {
    int g = i >> 11;
    int rem = i & 2047;
    int row = rem >> 7;
    int k8 = (rem & 127) * 8;
    *(short8*)&Ws[g * (16 * WROW) + row * WROW + k8] =
        *(const short8*)&Wh[((long)g * HID + (c0 + row)) * HID + k8];
  }
  __syncthreads();

  const int R = wv * 16 + ln;  // owned batch row
  const int F = c0 + q * 4;    // owned feature base
  const unsigned short* wpr = &Ws[0 * (16 * WROW) + ln * WROW + q * 8];
  const unsigned short* wpz = &Ws[1 * (16 * WROW) + ln * WROW + q * 8];
  const unsigned short* wpc = &Ws[2 * (16 * WROW) + ln * WROW + q * 8];
  const int frow = (wv * 16 + ln) * HROW + q * 8;        // fragment read base (shorts)
  const int lofs = (tid >> 4) * HROW + (tid & 15) * 8;   // staging write base (shorts)

  f32x4 h_st = {0.f, 0.f, 0.f, 0.f};
  f32x4 pg_r, pg_z, pg_c;
  {  // prefetch gx for t=0
    const float* g0 = &gx[((long)R * 3) * HID + F];
    pg_r = *(const f32x4*)(g0);
    pg_z = *(const f32x4*)(g0 + HID);
    pg_c = *(const f32x4*)(g0 + 2 * HID);
  }

  unsigned gen = 0;
  short8 hb[32];

  for (int t = 0; t < T_STEPS; ++t) {
    // ---- phase 1: r (critical), z (overlapped with barrier wait) ----
    f32x4 ar0 = {0.f, 0.f, 0.f, 0.f}, ar1 = {0.f, 0.f, 0.f, 0.f};
    staged_chain(h16, wpr, Hs[0], Hs[1], tid, frow, lofs, hb, ar0, ar1);
    {
      f32x4 accr = ar0 + ar1;
      float v0 = h_st[0] * (1.0f / (1.0f + __expf(-(pg_r[0] + accr[0]))));
      float v1 = h_st[1] * (1.0f / (1.0f + __expf(-(pg_r[1] + accr[1]))));
      float v2 = h_st[2] * (1.0f / (1.0f + __expf(-(pg_r[2] + accr[2]))));
      float v3 = h_st[3] * (1.0f / (1.0f + __expf(-(pg_r[3] + accr[3]))));
      st8_dev(hr16 + (long)R * HID + F, pack4bf(v0, v1, v2, v3));
    }
    ++gen;
    gbar_arrive(bar, gen, wgid);
    // z-chain overlapped with flag-visibility + poll (off critical path)
    f32x4 az = {0.f, 0.f, 0.f, 0.f};
#pragma unroll
    for (int kk = 0; kk < 32; ++kk) {
      short8 w = *(const short8*)(wpz + kk * 32);
      az = __builtin_amdgcn_mfma_f32_16x16x32_bf16(w, hb[kk], az, 0, 0, 0);
    }
    gbar_wait(bar, gen);

    // ---- phase 2: c + state update ----
    f32x4 ac0 = {0.f, 0.f, 0.f, 0.f}, ac1 = {0.f, 0.f, 0.f, 0.f};
    staged_chain(hr16, wpc, Hs[0], Hs[1], tid, frow, lofs, hb, ac0, ac1);
    long pos = (long)R * HID + F;
    long opos = ((long)t * BATCH + R) * HID + F;
    f32x4 hnv;
    u64 pk;
    {
      f32x4 accc = ac0 + ac1;
      unsigned short hq[4];
#pragma unroll
      for (int j = 0; j < 4; ++j) {
        float zz = 1.0f / (1.0f + __expf(-(pg_z[j] + az[j])));
        float cc = tanhf(pg_c[j] + accc[j]);
        float hn = zz * h_st[j] + (1.0f - zz) * cc;
        h_st[j] = hn; hnv[j] = hn; hq[j] = f2bf(hn);
      }
      pk = (u64)hq[0] | ((u64)hq[1] << 16) | ((u64)hq[2] << 32) | ((u64)hq[3] << 48);
      st8_dev(h16 + pos, pk);
    }
    ++gen;
    gbar_arrive(bar, gen, wgid);
    // off-critical-path work hidden under flag-visibility + poll:
    if (layer == 0) st8_dev(&ys16[opos], pk);
    else            st16_dev(&outh[opos], hnv);
    if (t == T_STEPS - 1) st16_dev(&outs[pos], hnv);
    if (t + 1 < T_STEPS) {  // gx prefetch for t+1 (drained by next phase-1 VMWAIT0)
      const float* g1 = &gx[(((long)(t + 1) * BATCH + R) * 3) * HID + F];
      pg_r = *(const f32x4*)(g1);
      pg_z = *(const f32x4*)(g1 + HID);
      pg_c = *(const f32x4*)(g1 + 2 * HID);
    }
    gbar_wait(bar, gen);
  }
}

// ---------------- launch ----------------
extern "C" void kernel_launch(void* const* d_in, const int* in_sizes, int n_in,
                              void* d_out, int out_size, void* d_ws, size_t ws_size,
                              hipStream_t stream) {
  const float* x = (const float*)d_in[0];
  const float* Wx = (const float*)d_in[1];
  const float* bx = (const float*)d_in[2];
  const float* Wh = (const float*)d_in[3];
  float* out = (float*)d_out;

  const size_t SZ_GX = (size_t)T_STEPS * BATCH * 3 * HID * 4;   // 402,653,184
  const size_t SZ_HID = (size_t)T_STEPS * BATCH * HID * 2;      // 67,108,864
  const size_t SZ_W16 = (size_t)2 * 3 * HID * HID * 2;          // 12,582,912
  const size_t NEEDED = SZ_GX + SZ_HID + 2 * SZ_W16 +
                        2 * (size_t)BATCH * HID * 2 + 256;
  if (ws_size < NEEDED) {
    k_sentinel<<<1, 64, 0, stream>>>(out);
    return;
  }

  char* ws = (char*)d_ws;
  size_t off = 0;
  float* gx32 = (float*)(ws + off); off += SZ_GX;
  unsigned short* hid16 = (unsigned short*)(ws + off); off += SZ_HID;
  unsigned short* Wx16 = (unsigned short*)(ws + off); off += SZ_W16;
  unsigned short* Wh16 = (unsigned short*)(ws + off); off += SZ_W16;
  unsigned short* h16 = (unsigned short*)(ws + off); off += (size_t)BATCH * HID * 2;
  unsigned short* hr16 = (unsigned short*)(ws + off); off += (size_t)BATCH * HID * 2;
  unsigned* bar = (unsigned*)(ws + off); off += 256;

  {
    int n4 = T_STEPS * BATCH * HID / 4;
    k_f32_to_bf16<<<(n4 + 255) / 256, 256, 0, stream>>>(x, hid16, n4);
  }
  {
    int n4 = 2 * 3 * HID * HID / 4;
    k_f32_to_bf16<<<(n4 + 255) / 256, 256, 0, stream>>>(Wx, Wx16, n4);
    k_f32_to_bf16<<<(n4 + 255) / 256, 256, 0, stream>>>(Wh, Wh16, n4);
  }

  float* outh = out;
  float* outs = out + (size_t)T_STEPS * BATCH * HID;

  for (int l = 0; l < 2; ++l) {
    k_gemm_bias<<<dim3(3072 / 128, 32768 / 128), 256, 0, stream>>>(
        hid16, Wx16 + (size_t)l * 3 * HID * HID, bx + (size_t)l * 3 * HID, gx32);
    hipMemsetAsync(h16, 0, (size_t)BATCH * HID * 2, stream);
    hipMemsetAsync(bar, 0, 256, stream);
    k_gru_rec<<<NWG, 256, 0, stream>>>(
        gx32, Wh16 + (size_t)l * 3 * HID * HID, h16, hr16,
        hid16, outh, outs + (size_t)l * BATCH * HID, bar, l);
  }
}